// Round 1
// baseline (1121.996 us; speedup 1.0000x reference)
//
#include <hip/hip_runtime.h>

#define N_NODES 100000
#define N_EDGES 3200000

// d_feat=32, d_cnn=128, d_lat=32, d_out=20

// ---------------- degree histogram (int atomics) ----------------
__global__ void hist_deg(const int* __restrict__ dst, int* __restrict__ cnt) {
    int e = blockIdx.x * blockDim.x + threadIdx.x;
    if (e < N_EDGES) atomicAdd(&cnt[dst[e]], 1);
}

// cnt(int, in-place) -> dinv(float) = rsqrt(cnt+1)
__global__ void deg_to_dinv(float* __restrict__ buf) {
    int i = blockIdx.x * blockDim.x + threadIdx.x;
    if (i < N_NODES) {
        int c = ((const int*)buf)[i];
        buf[i] = rsqrtf((float)c + 1.0f);
    }
}

// ---------------- fused encoder + GEMM1 + self-loop seed ----------------
// block = 256 threads = 4 nodes x 64 lanes. Grid = N_NODES/4 (exact).
__global__ void encoder_gemm1(const float* __restrict__ x, const float* __restrict__ cnn,
                              const float* __restrict__ fcW, const float* __restrict__ fcb,
                              const float* __restrict__ cnnW, const float* __restrict__ cnnb,
                              const float* __restrict__ W1, const float* __restrict__ b1,
                              const float* __restrict__ dinv,
                              float* __restrict__ h1, float* __restrict__ agg1) {
    __shared__ float s_fcW[32 * 32];
    __shared__ float s_cnnW[128 * 32];
    __shared__ float s_W1[64 * 32];
    __shared__ float s_fcb[32], s_cnnb[32], s_b1[32];
    __shared__ float s_x[4][32];
    __shared__ float s_cnn[4][128];
    __shared__ float s_h0[4][64];

    const int tid = threadIdx.x;
    for (int i = tid; i < 32 * 32; i += 256) s_fcW[i] = fcW[i];
    for (int i = tid; i < 128 * 32; i += 256) s_cnnW[i] = cnnW[i];
    for (int i = tid; i < 64 * 32; i += 256) s_W1[i] = W1[i];
    if (tid < 32) { s_fcb[tid] = fcb[tid]; s_cnnb[tid] = cnnb[tid]; s_b1[tid] = b1[tid]; }

    const int local = tid >> 6;   // node within block, 0..3
    const int lane = tid & 63;
    const int node = blockIdx.x * 4 + local;

    // stage input rows (coalesced)
    if (node < N_NODES) {
        if (lane < 32) s_x[local][lane] = x[node * 32 + lane];
        s_cnn[local][lane] = cnn[node * 128 + lane];
        s_cnn[local][lane + 64] = cnn[node * 128 + lane + 64];
    }
    __syncthreads();

    // h0 = relu(concat(x@fcW+fcb, cnn@cnnW+cnnb)); lane k computes h0[k]
    float h0v = 0.0f;
    if (node < N_NODES) {
        if (lane < 32) {
            float acc = s_fcb[lane];
            #pragma unroll
            for (int f = 0; f < 32; ++f) acc = fmaf(s_x[local][f], s_fcW[f * 32 + lane], acc);
            h0v = fmaxf(acc, 0.0f);
        } else {
            const int k = lane - 32;
            float acc = s_cnnb[k];
            #pragma unroll 8
            for (int f = 0; f < 128; ++f) acc = fmaf(s_cnn[local][f], s_cnnW[f * 32 + k], acc);
            h0v = fmaxf(acc, 0.0f);
        }
    }
    s_h0[local][lane] = h0v;
    __syncthreads();

    // h1 = h0 @ W1 ; agg1 seeded with self-loop + bias
    if (node < N_NODES && lane < 32) {
        float acc = 0.0f;
        #pragma unroll
        for (int k = 0; k < 64; ++k) acc = fmaf(s_h0[local][k], s_W1[k * 32 + lane], acc);
        const float di = dinv[node];
        h1[node * 32 + lane] = acc;
        agg1[node * 32 + lane] = acc * di * di + s_b1[lane];
    }
}

// ---------------- edge scatter, conv1 (32 cols) ----------------
// thread t -> edge = t>>5, col = t&31
__global__ void scatter1(const int* __restrict__ src, const int* __restrict__ dst,
                         const float* __restrict__ dinv,
                         const float* __restrict__ h1, float* __restrict__ agg1) {
    const int t = blockIdx.x * blockDim.x + threadIdx.x;
    const int e = t >> 5;
    const int c = t & 31;
    if (e < N_EDGES) {
        const int s = src[e], d = dst[e];
        const float w = dinv[s] * dinv[d];
        unsafeAtomicAdd(&agg1[d * 32 + c], h1[s * 32 + c] * w);
    }
}

// ---------------- relu + GEMM2 + self-loop seed of out ----------------
// block = 256 = 8 nodes x 32 lanes. Grid = N_NODES/8 (exact).
__global__ void gemm2_seed(const float* __restrict__ agg1, const float* __restrict__ W2,
                           const float* __restrict__ b2, const float* __restrict__ dinv,
                           float* __restrict__ h2, float* __restrict__ out) {
    __shared__ float sW2[32 * 20];
    __shared__ float sb2[20];
    __shared__ float sh[8][32];
    const int tid = threadIdx.x;
    for (int i = tid; i < 32 * 20; i += 256) sW2[i] = W2[i];
    if (tid < 20) sb2[tid] = b2[tid];

    const int local = tid >> 5, lane = tid & 31;
    const int node = blockIdx.x * 8 + local;
    float v = 0.0f;
    if (node < N_NODES) v = fmaxf(agg1[node * 32 + lane], 0.0f);
    sh[local][lane] = v;
    __syncthreads();

    if (node < N_NODES && lane < 20) {
        float acc = 0.0f;
        #pragma unroll
        for (int k = 0; k < 32; ++k) acc = fmaf(sh[local][k], sW2[k * 20 + lane], acc);
        const float di = dinv[node];
        h2[node * 20 + lane] = acc;
        out[node * 20 + lane] = acc * di * di + sb2[lane];
    }
}

// ---------------- edge scatter, conv2 (20 cols) ----------------
// block = 320 threads = 16 edges x 20 cols
__global__ void scatter2(const int* __restrict__ src, const int* __restrict__ dst,
                         const float* __restrict__ dinv,
                         const float* __restrict__ h2, float* __restrict__ out) {
    const int tid = threadIdx.x;
    const int e = blockIdx.x * 16 + tid / 20;
    const int c = tid % 20;
    if (e < N_EDGES) {
        const int s = src[e], d = dst[e];
        const float w = dinv[s] * dinv[d];
        unsafeAtomicAdd(&out[d * 20 + c], h2[s * 20 + c] * w);
    }
}

extern "C" void kernel_launch(void* const* d_in, const int* in_sizes, int n_in,
                              void* d_out, int out_size, void* d_ws, size_t ws_size,
                              hipStream_t stream) {
    const float* x    = (const float*)d_in[0];
    const float* cnn  = (const float*)d_in[1];
    const int*   ei   = (const int*)d_in[2];
    const float* fcW  = (const float*)d_in[3];
    const float* fcb  = (const float*)d_in[4];
    const float* cnnW = (const float*)d_in[5];
    const float* cnnb = (const float*)d_in[6];
    const float* W1   = (const float*)d_in[7];
    const float* b1   = (const float*)d_in[8];
    const float* W2   = (const float*)d_in[9];
    const float* b2   = (const float*)d_in[10];

    const int* srcp = ei;
    const int* dstp = ei + N_EDGES;

    float* ws   = (float*)d_ws;
    float* dinv = ws;                      // 100000 (padded to 100352)
    float* h1   = ws + 100352;             // N*32
    float* agg1 = h1 + N_NODES * 32;       // N*32
    float* h2   = agg1 + N_NODES * 32;     // N*20
    float* out  = (float*)d_out;

    // degree -> dinv
    hipMemsetAsync(dinv, 0, N_NODES * sizeof(float), stream);
    hist_deg<<<N_EDGES / 256, 256, 0, stream>>>(dstp, (int*)dinv);
    deg_to_dinv<<<(N_NODES + 255) / 256, 256, 0, stream>>>(dinv);

    // encoder + first linear + self-loop seed
    encoder_gemm1<<<N_NODES / 4, 256, 0, stream>>>(x, cnn, fcW, fcb, cnnW, cnnb, W1, b1,
                                                   dinv, h1, agg1);
    // conv1 edge aggregation
    scatter1<<<(N_EDGES * 32) / 256, 256, 0, stream>>>(srcp, dstp, dinv, h1, agg1);

    // relu + second linear + seed out
    gemm2_seed<<<N_NODES / 8, 256, 0, stream>>>(agg1, W2, b2, dinv, h2, out);

    // conv2 edge aggregation into out
    scatter2<<<N_EDGES / 16, 320, 0, stream>>>(srcp, dstp, dinv, h2, out);
}

// Round 4
// 985.496 us; speedup vs baseline: 1.1385x; 1.1385x over previous
//
#include <hip/hip_runtime.h>

#define N_NODES 100000
#define N_EDGES 3200000
#define SCAN_NB 391   // ceil(100000/256)

// ---------------- degree histogram (int atomics) ----------------
__global__ void hist_deg(const int* __restrict__ dst, int* __restrict__ cnt) {
    int e = blockIdx.x * blockDim.x + threadIdx.x;
    atomicAdd(&cnt[dst[e]], 1);   // grid exact: 12500*256 == N_EDGES
}

// cnt(int, in-place) -> dinv(float) = rsqrt(cnt+1)
__global__ void deg_to_dinv(float* __restrict__ buf) {
    int i = blockIdx.x * blockDim.x + threadIdx.x;
    if (i < N_NODES) {
        int c = ((const int*)buf)[i];
        buf[i] = rsqrtf((float)c + 1.0f);
    }
}

// ---------------- 3-kernel exclusive scan of cnt -> row_ptr ----------------
__global__ void scan1(const int* __restrict__ cnt, int* __restrict__ row,
                      int* __restrict__ bsum) {
    __shared__ int s[256];
    const int i = blockIdx.x * 256 + threadIdx.x;
    const int v = (i < N_NODES) ? cnt[i] : 0;
    s[threadIdx.x] = v;
    __syncthreads();
    #pragma unroll
    for (int off = 1; off < 256; off <<= 1) {
        int t = (threadIdx.x >= off) ? s[threadIdx.x - off] : 0;
        __syncthreads();
        s[threadIdx.x] += t;
        __syncthreads();
    }
    if (i < N_NODES) row[i] = s[threadIdx.x] - v;   // exclusive
    if (threadIdx.x == 255) bsum[blockIdx.x] = s[255];
}

__global__ void scan2(int* __restrict__ bsum) {
    __shared__ int s[512];
    const int v = (threadIdx.x < SCAN_NB) ? bsum[threadIdx.x] : 0;
    s[threadIdx.x] = v;
    __syncthreads();
    #pragma unroll
    for (int off = 1; off < 512; off <<= 1) {
        int t = (threadIdx.x >= off) ? s[threadIdx.x - off] : 0;
        __syncthreads();
        s[threadIdx.x] += t;
        __syncthreads();
    }
    if (threadIdx.x < SCAN_NB) bsum[threadIdx.x] = s[threadIdx.x] - v;  // exclusive
}

__global__ void scan3(int* __restrict__ row, const int* __restrict__ bsum) {
    const int i = blockIdx.x * 256 + threadIdx.x;
    if (i < N_NODES) row[i] += bsum[blockIdx.x];
}

// ---------------- CSR fill (counting sort by dst) ----------------
// Uses atomicAdd on row_ptr itself; afterwards row[d] == END of node d's range
// (start of node d is row[d-1], or 0 for d==0).
__global__ void fill_csr(const int* __restrict__ src, const int* __restrict__ dst,
                         int* __restrict__ row, int* __restrict__ sorted_src) {
    const int e = blockIdx.x * blockDim.x + threadIdx.x;   // grid exact
    const int d = dst[e];
    const int pos = atomicAdd(&row[d], 1);
    sorted_src[pos] = src[e];
}

// ---------------- persistent fused encoder + GEMM1 ----------------
// block = 256 threads = 4 nodes x 64 lanes; grid-stride over 25000 tiles.
// NOTE: no cross-wave LDS sharing (each wave reads only its own s_x/s_cnn/s_h0
// rows), so the in-loop barriers are only wave-scheduling fences.
__global__ __launch_bounds__(256) void encoder_gemm1(
        const float* __restrict__ x, const float* __restrict__ cnn,
        const float* __restrict__ fcW, const float* __restrict__ fcb,
        const float* __restrict__ cnnW, const float* __restrict__ cnnb,
        const float* __restrict__ W1, float* __restrict__ h1) {
    __shared__ float s_fcW[32 * 32];
    __shared__ float s_cnnW[128 * 32];
    __shared__ float s_W1[64 * 32];
    __shared__ float s_fcb[32], s_cnnb[32];
    __shared__ float s_x[4][32];
    __shared__ float s_cnn[4][128];
    __shared__ float s_h0[4][64];

    const int tid = threadIdx.x;
    for (int i = tid; i < 32 * 32; i += 256) s_fcW[i] = fcW[i];
    for (int i = tid; i < 128 * 32; i += 256) s_cnnW[i] = cnnW[i];
    for (int i = tid; i < 64 * 32; i += 256) s_W1[i] = W1[i];
    if (tid < 32) { s_fcb[tid] = fcb[tid]; s_cnnb[tid] = cnnb[tid]; }
    __syncthreads();

    const int local = tid >> 6;   // 0..3
    const int lane = tid & 63;

    for (int tile = blockIdx.x; tile < N_NODES / 4; tile += gridDim.x) {
        const int node = tile * 4 + local;
        // stage input rows (coalesced); no bounds check: 25000*4 == N_NODES
        if (lane < 32) s_x[local][lane] = x[node * 32 + lane];
        s_cnn[local][lane] = cnn[node * 128 + lane];
        s_cnn[local][lane + 64] = cnn[node * 128 + lane + 64];
        __syncthreads();

        // h0 = relu(concat(x@fcW+fcb, cnn@cnnW+cnnb)); lane k owns h0[k]
        float h0v;
        if (lane < 32) {
            float acc = s_fcb[lane];
            #pragma unroll
            for (int f = 0; f < 32; ++f) acc = fmaf(s_x[local][f], s_fcW[f * 32 + lane], acc);
            h0v = fmaxf(acc, 0.0f);
        } else {
            const int k = lane - 32;
            float acc = s_cnnb[k];
            #pragma unroll 8
            for (int f = 0; f < 128; ++f) acc = fmaf(s_cnn[local][f], s_cnnW[f * 32 + k], acc);
            h0v = fmaxf(acc, 0.0f);
        }
        s_h0[local][lane] = h0v;
        __syncthreads();

        // h1 = h0 @ W1
        if (lane < 32) {
            float acc = 0.0f;
            #pragma unroll
            for (int k = 0; k < 64; ++k) acc = fmaf(s_h0[local][k], s_W1[k * 32 + lane], acc);
            h1[node * 32 + lane] = acc;
        }
    }
}

// ---------------- conv1 gather + ReLU + GEMM2, fused ----------------
// block = 256 = 8 nodes x 32 lanes; grid = 12500 (exact). Writes h2 only.
__global__ __launch_bounds__(256) void conv1_fused(
        const float* __restrict__ h1, const int* __restrict__ row,
        const int* __restrict__ sorted_src, const float* __restrict__ dinv,
        const float* __restrict__ b1, const float* __restrict__ W2,
        float* __restrict__ h2) {
    __shared__ float sW2[32 * 20];
    __shared__ float sb1[32];
    __shared__ float sa[8][33];
    const int tid = threadIdx.x;
    for (int i = tid; i < 32 * 20; i += 256) sW2[i] = W2[i];
    if (tid < 32) sb1[tid] = b1[tid];
    // R3 FIX: sb1 is written by wave 0 but read by all 4 waves immediately
    // below. Without this barrier the compiler hoists the ds_read of sb1 and
    // waves 1-3 read stale LDS (leftover encoder weights, |w|<=0.27 — matched
    // the observed absmax 0.244).
    __syncthreads();

    const int local = tid >> 5, lane = tid & 31;
    const int node = blockIdx.x * 8 + local;

    const float di = dinv[node];
    float acc = h1[node * 32 + lane] * di * di + sb1[lane];
    const int start = (node == 0) ? 0 : row[node - 1];
    const int end = row[node];
    for (int i = start; i < end; ++i) {
        const int s = sorted_src[i];
        acc = fmaf(h1[s * 32 + lane], dinv[s] * di, acc);
    }
    sa[local][lane] = fmaxf(acc, 0.0f);   // ReLU
    __syncthreads();

    if (lane < 20) {
        float o = 0.0f;
        #pragma unroll
        for (int k = 0; k < 32; ++k) o = fmaf(sa[local][k], sW2[k * 20 + lane], o);
        h2[node * 20 + lane] = o;
    }
}

// ---------------- conv2 gather (final output) ----------------
// block = 256 = 8 nodes x 32 lanes (lanes 0..19 active); grid = 12500.
__global__ __launch_bounds__(256) void conv2_gather(
        const float* __restrict__ h2, const int* __restrict__ row,
        const int* __restrict__ sorted_src, const float* __restrict__ dinv,
        const float* __restrict__ b2, float* __restrict__ out) {
    __shared__ float sb2[20];
    const int tid = threadIdx.x;
    if (tid < 20) sb2[tid] = b2[tid];
    __syncthreads();

    const int local = tid >> 5, lane = tid & 31;
    const int node = blockIdx.x * 8 + local;
    if (lane < 20) {
        const float di = dinv[node];
        float acc = h2[node * 20 + lane] * di * di + sb2[lane];
        const int start = (node == 0) ? 0 : row[node - 1];
        const int end = row[node];
        for (int i = start; i < end; ++i) {
            const int s = sorted_src[i];
            acc = fmaf(h2[s * 20 + lane], dinv[s] * di, acc);
        }
        out[node * 20 + lane] = acc;
    }
}

extern "C" void kernel_launch(void* const* d_in, const int* in_sizes, int n_in,
                              void* d_out, int out_size, void* d_ws, size_t ws_size,
                              hipStream_t stream) {
    const float* x    = (const float*)d_in[0];
    const float* cnn  = (const float*)d_in[1];
    const int*   ei   = (const int*)d_in[2];
    const float* fcW  = (const float*)d_in[3];
    const float* fcb  = (const float*)d_in[4];
    const float* cnnW = (const float*)d_in[5];
    const float* cnnb = (const float*)d_in[6];
    const float* W1   = (const float*)d_in[7];
    const float* b1   = (const float*)d_in[8];
    const float* W2   = (const float*)d_in[9];
    const float* b2   = (const float*)d_in[10];

    const int* srcp = ei;
    const int* dstp = ei + N_EDGES;

    // workspace layout (4-byte units)
    float* ws      = (float*)d_ws;
    float* dinv    = ws;                        // [100352]  int cnt -> float dinv
    int*   row     = (int*)(ws + 100352);       // [100352]  row_ptr
    int*   bsum    = (int*)(ws + 201216);       // [512]
    int*   sorted  = (int*)(ws + 201728);       // [N_EDGES]
    float* h1      = ws + 201728 + N_EDGES;     // [N*32]
    float* h2      = h1 + N_NODES * 32;         // [N*20]
    float* out     = (float*)d_out;

    // --- CSR build ---
    hipMemsetAsync(dinv, 0, N_NODES * sizeof(int), stream);
    hist_deg<<<N_EDGES / 256, 256, 0, stream>>>(dstp, (int*)dinv);
    scan1<<<SCAN_NB, 256, 0, stream>>>((const int*)dinv, row, bsum);
    scan2<<<1, 512, 0, stream>>>(bsum);
    scan3<<<SCAN_NB, 256, 0, stream>>>(row, bsum);
    deg_to_dinv<<<392, 256, 0, stream>>>(dinv);
    fill_csr<<<N_EDGES / 256, 256, 0, stream>>>(srcp, dstp, row, sorted);

    // --- encoder + first linear (persistent) ---
    encoder_gemm1<<<1280, 256, 0, stream>>>(x, cnn, fcW, fcb, cnnW, cnnb, W1, h1);

    // --- conv1 gather + relu + gemm2 ---
    conv1_fused<<<N_NODES / 8, 256, 0, stream>>>(h1, row, sorted, dinv, b1, W2, h2);

    // --- conv2 gather -> out ---
    conv2_gather<<<N_NODES / 8, 256, 0, stream>>>(h2, row, sorted, dinv, b2, out);
}

// Round 7
// 700.167 us; speedup vs baseline: 1.6025x; 1.4075x over previous
//
#include <hip/hip_runtime.h>

#define N_NODES 100000
#define N_EDGES 3200000
#define NBKT 391     // ceil(100000/256): buckets of 256 dst nodes
#define EPB 4096     // edges per block in bucket passes
#define NBLK_E 782   // ceil(N_EDGES/EPB)
#define SCAN_NB 391  // ceil(100000/256) node-scan blocks

// ---------- pass A: per-bucket edge counts (LDS-aggregated) ----------
__global__ __launch_bounds__(256) void bucket_hist(const int* __restrict__ dst,
                                                   int* __restrict__ bktcnt) {
    __shared__ int h[NBKT];
    for (int i = threadIdx.x; i < NBKT; i += 256) h[i] = 0;
    __syncthreads();
    const int base = blockIdx.x * EPB;
    #pragma unroll
    for (int k = 0; k < 16; ++k) {
        const int e = base + k * 256 + threadIdx.x;
        if (e < N_EDGES) atomicAdd(&h[dst[e] >> 8], 1);
    }
    __syncthreads();
    for (int i = threadIdx.x; i < NBKT; i += 256)
        if (h[i]) atomicAdd(&bktcnt[i], h[i]);
}

// ---------- scan of bucket counts -> bases + cursors (1 block) ----------
__global__ void bucket_scan(const int* __restrict__ bktcnt, int* __restrict__ bktbase,
                            int* __restrict__ bktcur) {
    __shared__ int s[512];
    const int t = threadIdx.x;
    const int v = (t < NBKT) ? bktcnt[t] : 0;
    s[t] = v;
    __syncthreads();
    #pragma unroll
    for (int off = 1; off < 512; off <<= 1) {
        const int u = (t >= off) ? s[t - off] : 0;
        __syncthreads();
        s[t] += u;
        __syncthreads();
    }
    // exclusive base; t==NBKT has v=0 so base[NBKT] = total = N_EDGES
    if (t <= NBKT) {
        const int b = s[t] - v;
        bktbase[t] = b;
        if (t < NBKT) bktcur[t] = b;
    }
}

// ---------- pass B: chunked scatter of packed (src<<8 | dstlocal) ----------
// Each block bins EPB edges, reserves one contiguous chunk per bucket with a
// single global atomic, then writes densely -> line fills are block(XCD)-local.
__global__ __launch_bounds__(256) void bucket_scatter(const int* __restrict__ src,
                                                      const int* __restrict__ dst,
                                                      int* __restrict__ bktcur,
                                                      int* __restrict__ pairs) {
    __shared__ int h[NBKT], gb[NBKT], lc[NBKT];
    for (int i = threadIdx.x; i < NBKT; i += 256) h[i] = 0;
    __syncthreads();
    const int base = blockIdx.x * EPB;
    int v[16], bk[16];
    #pragma unroll
    for (int k = 0; k < 16; ++k) {
        const int e = base + k * 256 + threadIdx.x;
        if (e < N_EDGES) {
            const int d = dst[e];
            bk[k] = d >> 8;
            v[k] = (src[e] << 8) | (d & 255);
            atomicAdd(&h[bk[k]], 1);
        } else {
            bk[k] = -1;
        }
    }
    __syncthreads();
    for (int i = threadIdx.x; i < NBKT; i += 256) {
        gb[i] = h[i] ? atomicAdd(&bktcur[i], h[i]) : 0;
        lc[i] = 0;
    }
    __syncthreads();
    #pragma unroll
    for (int k = 0; k < 16; ++k) {
        if (bk[k] >= 0) {
            const int pos = gb[bk[k]] + atomicAdd(&lc[bk[k]], 1);
            pairs[pos] = v[k];
        }
    }
}

// ---------- pass C1: per-bucket dst degrees via LDS hist ----------
__global__ __launch_bounds__(256) void bucket_deg(const int* __restrict__ pairs,
                                                  const int* __restrict__ bktbase,
                                                  int* __restrict__ deg) {
    __shared__ int h[256];
    h[threadIdx.x] = 0;
    __syncthreads();
    const int b = blockIdx.x;
    const int s0 = bktbase[b], s1 = bktbase[b + 1];
    for (int i = s0 + threadIdx.x; i < s1; i += 256) atomicAdd(&h[pairs[i] & 255], 1);
    __syncthreads();
    const int node = (b << 8) + threadIdx.x;
    if (node < N_NODES) deg[node] = h[threadIdx.x];
}

// ---------- 3-kernel exclusive scan of deg -> row (row preserved) ----------
__global__ void scan1(const int* __restrict__ cnt, int* __restrict__ row,
                      int* __restrict__ bsum) {
    __shared__ int s[256];
    const int i = blockIdx.x * 256 + threadIdx.x;
    const int v = (i < N_NODES) ? cnt[i] : 0;
    s[threadIdx.x] = v;
    __syncthreads();
    #pragma unroll
    for (int off = 1; off < 256; off <<= 1) {
        const int t = (threadIdx.x >= off) ? s[threadIdx.x - off] : 0;
        __syncthreads();
        s[threadIdx.x] += t;
        __syncthreads();
    }
    if (i < N_NODES) row[i] = s[threadIdx.x] - v;
    if (threadIdx.x == 255) bsum[blockIdx.x] = s[255];
}

__global__ void scan2(int* __restrict__ bsum) {
    __shared__ int s[512];
    const int v = (threadIdx.x < SCAN_NB) ? bsum[threadIdx.x] : 0;
    s[threadIdx.x] = v;
    __syncthreads();
    #pragma unroll
    for (int off = 1; off < 512; off <<= 1) {
        const int t = (threadIdx.x >= off) ? s[threadIdx.x - off] : 0;
        __syncthreads();
        s[threadIdx.x] += t;
        __syncthreads();
    }
    if (threadIdx.x < SCAN_NB) bsum[threadIdx.x] = s[threadIdx.x] - v;
}

__global__ void scan3(int* __restrict__ row, const int* __restrict__ bsum) {
    const int i = blockIdx.x * 256 + threadIdx.x;
    if (i < N_NODES) row[i] += bsum[blockIdx.x];
    if (blockIdx.x == 0 && threadIdx.x == 0) row[N_NODES] = N_EDGES;  // sentinel
}

// deg(int, in-place) -> dinv(float) = rsqrt(deg+1)
__global__ void deg_to_dinv(float* __restrict__ buf) {
    const int i = blockIdx.x * blockDim.x + threadIdx.x;
    if (i < N_NODES) {
        const int c = ((const int*)buf)[i];
        buf[i] = rsqrtf((float)c + 1.0f);
    }
}

// ---------- pass C2: per-bucket CSR fill (bucket region = one block/XCD) ----------
__global__ __launch_bounds__(256) void csr_fill(const int* __restrict__ pairs,
                                                const int* __restrict__ bktbase,
                                                const int* __restrict__ row,
                                                int* __restrict__ sorted_src) {
    __shared__ int lc[256];
    lc[threadIdx.x] = 0;
    __syncthreads();
    const int b = blockIdx.x;
    const int s0 = bktbase[b], s1 = bktbase[b + 1];
    const int nbase = b << 8;
    for (int i = s0 + threadIdx.x; i < s1; i += 256) {
        const int p = pairs[i];
        const int dl = p & 255;
        const int pos = row[nbase + dl] + atomicAdd(&lc[dl], 1);
        sorted_src[pos] = p >> 8;
    }
}

// ---------- persistent fused encoder + GEMM1 (unchanged from R4) ----------
__global__ __launch_bounds__(256) void encoder_gemm1(
        const float* __restrict__ x, const float* __restrict__ cnn,
        const float* __restrict__ fcW, const float* __restrict__ fcb,
        const float* __restrict__ cnnW, const float* __restrict__ cnnb,
        const float* __restrict__ W1, float* __restrict__ h1) {
    __shared__ float s_fcW[32 * 32];
    __shared__ float s_cnnW[128 * 32];
    __shared__ float s_W1[64 * 32];
    __shared__ float s_fcb[32], s_cnnb[32];
    __shared__ float s_x[4][32];
    __shared__ float s_cnn[4][128];
    __shared__ float s_h0[4][64];

    const int tid = threadIdx.x;
    for (int i = tid; i < 32 * 32; i += 256) s_fcW[i] = fcW[i];
    for (int i = tid; i < 128 * 32; i += 256) s_cnnW[i] = cnnW[i];
    for (int i = tid; i < 64 * 32; i += 256) s_W1[i] = W1[i];
    if (tid < 32) { s_fcb[tid] = fcb[tid]; s_cnnb[tid] = cnnb[tid]; }
    __syncthreads();

    const int local = tid >> 6;
    const int lane = tid & 63;

    for (int tile = blockIdx.x; tile < N_NODES / 4; tile += gridDim.x) {
        const int node = tile * 4 + local;
        if (lane < 32) s_x[local][lane] = x[node * 32 + lane];
        s_cnn[local][lane] = cnn[node * 128 + lane];
        s_cnn[local][lane + 64] = cnn[node * 128 + lane + 64];
        __syncthreads();

        float h0v;
        if (lane < 32) {
            float acc = s_fcb[lane];
            #pragma unroll
            for (int f = 0; f < 32; ++f) acc = fmaf(s_x[local][f], s_fcW[f * 32 + lane], acc);
            h0v = fmaxf(acc, 0.0f);
        } else {
            const int k = lane - 32;
            float acc = s_cnnb[k];
            #pragma unroll 8
            for (int f = 0; f < 128; ++f) acc = fmaf(s_cnn[local][f], s_cnnW[f * 32 + k], acc);
            h0v = fmaxf(acc, 0.0f);
        }
        s_h0[local][lane] = h0v;
        __syncthreads();

        if (lane < 32) {
            float acc = 0.0f;
            #pragma unroll
            for (int k = 0; k < 64; ++k) acc = fmaf(s_h0[local][k], s_W1[k * 32 + lane], acc);
            h1[node * 32 + lane] = acc;
        }
    }
}

// ---------- conv1: gather + ReLU + GEMM2 (wave-convergent: 1 node / wave) ----------
__global__ __launch_bounds__(256) void conv1_fused(
        const float* __restrict__ h1, const int* __restrict__ row,
        const int* __restrict__ sorted_src, const float* __restrict__ dinv,
        const float* __restrict__ b1, const float* __restrict__ W2,
        float* __restrict__ h2) {
    __shared__ float sW2[32 * 20];
    __shared__ float sb1[32];
    __shared__ float sa[4][33];
    const int tid = threadIdx.x;
    for (int i = tid; i < 32 * 20; i += 256) sW2[i] = W2[i];
    if (tid < 32) sb1[tid] = b1[tid];
    __syncthreads();   // stage-before-use barrier (R3 lesson)

    const int wid = tid >> 6;      // node within block
    const int lane = tid & 63;
    const int col = lane & 31;
    const int half = lane >> 5;
    const int node = blockIdx.x * 4 + wid;   // grid 25000 exact

    const float di = dinv[node];
    float acc = (half == 0) ? h1[node * 32 + col] * di * di + sb1[col] : 0.0f;
    const int start = row[node], end = row[node + 1];
    for (int i = start + half; i < end; i += 2) {
        const int s = sorted_src[i];
        acc = fmaf(h1[s * 32 + col], dinv[s] * di, acc);
    }
    acc += __shfl_xor(acc, 32);    // combine the two half-wave partials
    if (half == 0) sa[wid][col] = fmaxf(acc, 0.0f);
    __syncthreads();

    if (lane < 20) {
        float o = 0.0f;
        #pragma unroll
        for (int k = 0; k < 32; ++k) o = fmaf(sa[wid][k], sW2[k * 20 + lane], o);
        h2[node * 20 + lane] = o;
    }
}

// ---------- conv2: gather -> out (wave-convergent) ----------
__global__ __launch_bounds__(256) void conv2_gather(
        const float* __restrict__ h2, const int* __restrict__ row,
        const int* __restrict__ sorted_src, const float* __restrict__ dinv,
        const float* __restrict__ b2, float* __restrict__ out) {
    __shared__ float sb2[20];
    const int tid = threadIdx.x;
    if (tid < 20) sb2[tid] = b2[tid];
    __syncthreads();

    const int wid = tid >> 6, lane = tid & 63;
    const int col = lane & 31, half = lane >> 5;
    const int node = blockIdx.x * 4 + wid;

    const float di = dinv[node];
    float acc = 0.0f;
    if (half == 0 && col < 20) acc = h2[node * 20 + col] * di * di + sb2[col];
    const int start = row[node], end = row[node + 1];
    for (int i = start + half; i < end; i += 2) {
        const int s = sorted_src[i];
        if (col < 20) acc = fmaf(h2[s * 20 + col], dinv[s] * di, acc);
    }
    acc += __shfl_xor(acc, 32);
    if (half == 0 && col < 20) out[node * 20 + col] = acc;
}

extern "C" void kernel_launch(void* const* d_in, const int* in_sizes, int n_in,
                              void* d_out, int out_size, void* d_ws, size_t ws_size,
                              hipStream_t stream) {
    const float* x    = (const float*)d_in[0];
    const float* cnn  = (const float*)d_in[1];
    const int*   ei   = (const int*)d_in[2];
    const float* fcW  = (const float*)d_in[3];
    const float* fcb  = (const float*)d_in[4];
    const float* cnnW = (const float*)d_in[5];
    const float* cnnb = (const float*)d_in[6];
    const float* W1   = (const float*)d_in[7];
    const float* b1   = (const float*)d_in[8];
    const float* W2   = (const float*)d_in[9];
    const float* b2   = (const float*)d_in[10];

    const int* srcp = ei;
    const int* dstp = ei + N_EDGES;

    // workspace layout (4-byte units)
    float* ws      = (float*)d_ws;
    float* dinv    = ws;                        // [100352] int deg -> float dinv
    int*   row     = (int*)(ws + 100352);       // [100608] row_ptr (N+1 used)
    int*   bsum    = (int*)(ws + 200960);       // [512]
    int*   bktcnt  = (int*)(ws + 201472);       // [512]
    int*   bktbase = (int*)(ws + 201984);       // [512] (NBKT+1 used)
    int*   bktcur  = (int*)(ws + 202496);       // [512]
    int*   pairs   = (int*)(ws + 203008);       // [N_EDGES] packed (src<<8|dl)
    int*   sorted  = (int*)(ws + 203008 + N_EDGES);          // [N_EDGES]
    float* h1      = ws + 203008 + 2 * N_EDGES;              // [N*32]
    float* h2      = h1 + N_NODES * 32;                      // [N*20]
    float* out     = (float*)d_out;
    int*   deg     = (int*)dinv;

    // --- bucketed CSR build ---
    hipMemsetAsync(bktcnt, 0, 512 * sizeof(int), stream);
    bucket_hist<<<NBLK_E, 256, 0, stream>>>(dstp, bktcnt);
    bucket_scan<<<1, 512, 0, stream>>>(bktcnt, bktbase, bktcur);
    bucket_scatter<<<NBLK_E, 256, 0, stream>>>(srcp, dstp, bktcur, pairs);
    bucket_deg<<<NBKT, 256, 0, stream>>>(pairs, bktbase, deg);
    scan1<<<SCAN_NB, 256, 0, stream>>>(deg, row, bsum);
    scan2<<<1, 512, 0, stream>>>(bsum);
    scan3<<<SCAN_NB, 256, 0, stream>>>(row, bsum);
    deg_to_dinv<<<392, 256, 0, stream>>>(dinv);
    csr_fill<<<NBKT, 256, 0, stream>>>(pairs, bktbase, row, sorted);

    // --- encoder + first linear (persistent) ---
    encoder_gemm1<<<1280, 256, 0, stream>>>(x, cnn, fcW, fcb, cnnW, cnnb, W1, h1);

    // --- conv1 gather + relu + gemm2 ---
    conv1_fused<<<N_NODES / 4, 256, 0, stream>>>(h1, row, sorted, dinv, b1, W2, h2);

    // --- conv2 gather -> out ---
    conv2_gather<<<N_NODES / 4, 256, 0, stream>>>(h2, row, sorted, dinv, b2, out);
}

// Round 8
// 537.731 us; speedup vs baseline: 2.0865x; 1.3021x over previous
//
#include <hip/hip_runtime.h>

#define N_NODES 100000
#define N_EDGES 3200000
#define NBKT 391     // ceil(100000/256): buckets of 256 dst nodes
#define EPB 4096     // edges per block in bucket passes
#define NBLK_E 782   // ceil(N_EDGES/EPB)
#define SCAN_NB 391  // ceil(100000/256) node-scan blocks

// bf16 helpers (round-to-nearest-even pack, cheap unpack)
__device__ __forceinline__ unsigned short f2bf(float f) {
    unsigned int u = __float_as_uint(f);
    u += 0x7fff + ((u >> 16) & 1);
    return (unsigned short)(u >> 16);
}
__device__ __forceinline__ float bf2f(unsigned short h) {
    return __uint_as_float(((unsigned int)h) << 16);
}

// ---------- pass A: per-bucket edge counts (LDS-aggregated) ----------
__global__ __launch_bounds__(256) void bucket_hist(const int* __restrict__ dst,
                                                   int* __restrict__ bktcnt) {
    __shared__ int h[NBKT];
    for (int i = threadIdx.x; i < NBKT; i += 256) h[i] = 0;
    __syncthreads();
    const int base = blockIdx.x * EPB;
    #pragma unroll
    for (int k = 0; k < 16; ++k) {
        const int e = base + k * 256 + threadIdx.x;
        if (e < N_EDGES) atomicAdd(&h[dst[e] >> 8], 1);
    }
    __syncthreads();
    for (int i = threadIdx.x; i < NBKT; i += 256)
        if (h[i]) atomicAdd(&bktcnt[i], h[i]);
}

// ---------- scan of bucket counts -> bases + cursors (1 block) ----------
__global__ void bucket_scan(const int* __restrict__ bktcnt, int* __restrict__ bktbase,
                            int* __restrict__ bktcur) {
    __shared__ int s[512];
    const int t = threadIdx.x;
    const int v = (t < NBKT) ? bktcnt[t] : 0;
    s[t] = v;
    __syncthreads();
    #pragma unroll
    for (int off = 1; off < 512; off <<= 1) {
        const int u = (t >= off) ? s[t - off] : 0;
        __syncthreads();
        s[t] += u;
        __syncthreads();
    }
    if (t <= NBKT) {
        const int b = s[t] - v;
        bktbase[t] = b;
        if (t < NBKT) bktcur[t] = b;
    }
}

// ---------- pass B: chunked scatter of packed (src<<8 | dstlocal) ----------
__global__ __launch_bounds__(256) void bucket_scatter(const int* __restrict__ src,
                                                      const int* __restrict__ dst,
                                                      int* __restrict__ bktcur,
                                                      int* __restrict__ pairs) {
    __shared__ int h[NBKT], gb[NBKT], lc[NBKT];
    for (int i = threadIdx.x; i < NBKT; i += 256) h[i] = 0;
    __syncthreads();
    const int base = blockIdx.x * EPB;
    int v[16], bk[16];
    #pragma unroll
    for (int k = 0; k < 16; ++k) {
        const int e = base + k * 256 + threadIdx.x;
        if (e < N_EDGES) {
            const int d = dst[e];
            bk[k] = d >> 8;
            v[k] = (src[e] << 8) | (d & 255);
            atomicAdd(&h[bk[k]], 1);
        } else {
            bk[k] = -1;
        }
    }
    __syncthreads();
    for (int i = threadIdx.x; i < NBKT; i += 256) {
        gb[i] = h[i] ? atomicAdd(&bktcur[i], h[i]) : 0;
        lc[i] = 0;
    }
    __syncthreads();
    #pragma unroll
    for (int k = 0; k < 16; ++k) {
        if (bk[k] >= 0) {
            const int pos = gb[bk[k]] + atomicAdd(&lc[bk[k]], 1);
            pairs[pos] = v[k];
        }
    }
}

// ---------- pass C1: per-bucket dst degrees via LDS hist; also emits dinv ----------
__global__ __launch_bounds__(256) void bucket_deg(const int* __restrict__ pairs,
                                                  const int* __restrict__ bktbase,
                                                  int* __restrict__ deg,
                                                  float* __restrict__ dinv) {
    __shared__ int h[256];
    h[threadIdx.x] = 0;
    __syncthreads();
    const int b = blockIdx.x;
    const int s0 = bktbase[b], s1 = bktbase[b + 1];
    for (int i = s0 + threadIdx.x; i < s1; i += 256) atomicAdd(&h[pairs[i] & 255], 1);
    __syncthreads();
    const int node = (b << 8) + threadIdx.x;
    if (node < N_NODES) {
        const int c = h[threadIdx.x];
        deg[node] = c;
        dinv[node] = rsqrtf((float)c + 1.0f);
    }
}

// ---------- 3-kernel exclusive scan of deg -> row ----------
__global__ void scan1(const int* __restrict__ cnt, int* __restrict__ row,
                      int* __restrict__ bsum) {
    __shared__ int s[256];
    const int i = blockIdx.x * 256 + threadIdx.x;
    const int v = (i < N_NODES) ? cnt[i] : 0;
    s[threadIdx.x] = v;
    __syncthreads();
    #pragma unroll
    for (int off = 1; off < 256; off <<= 1) {
        const int t = (threadIdx.x >= off) ? s[threadIdx.x - off] : 0;
        __syncthreads();
        s[threadIdx.x] += t;
        __syncthreads();
    }
    if (i < N_NODES) row[i] = s[threadIdx.x] - v;
    if (threadIdx.x == 255) bsum[blockIdx.x] = s[255];
}

__global__ void scan2(int* __restrict__ bsum) {
    __shared__ int s[512];
    const int v = (threadIdx.x < SCAN_NB) ? bsum[threadIdx.x] : 0;
    s[threadIdx.x] = v;
    __syncthreads();
    #pragma unroll
    for (int off = 1; off < 512; off <<= 1) {
        const int t = (threadIdx.x >= off) ? s[threadIdx.x - off] : 0;
        __syncthreads();
        s[threadIdx.x] += t;
        __syncthreads();
    }
    if (threadIdx.x < SCAN_NB) bsum[threadIdx.x] = s[threadIdx.x] - v;
}

__global__ void scan3(int* __restrict__ row, const int* __restrict__ bsum) {
    const int i = blockIdx.x * 256 + threadIdx.x;
    if (i < N_NODES) row[i] += bsum[blockIdx.x];
    if (blockIdx.x == 0 && threadIdx.x == 0) row[N_NODES] = N_EDGES;  // sentinel
}

// ---------- pass C2: per-bucket CSR fill ----------
__global__ __launch_bounds__(256) void csr_fill(const int* __restrict__ pairs,
                                                const int* __restrict__ bktbase,
                                                const int* __restrict__ row,
                                                int* __restrict__ sorted_src) {
    __shared__ int lc[256];
    lc[threadIdx.x] = 0;
    __syncthreads();
    const int b = blockIdx.x;
    const int s0 = bktbase[b], s1 = bktbase[b + 1];
    const int nbase = b << 8;
    for (int i = s0 + threadIdx.x; i < s1; i += 256) {
        const int p = pairs[i];
        const int dl = p & 255;
        const int pos = row[nbase + dl] + atomicAdd(&lc[dl], 1);
        sorted_src[pos] = p >> 8;
    }
}

// ---------- persistent fused encoder + GEMM1 (h1 now bf16) ----------
__global__ __launch_bounds__(256) void encoder_gemm1(
        const float* __restrict__ x, const float* __restrict__ cnn,
        const float* __restrict__ fcW, const float* __restrict__ fcb,
        const float* __restrict__ cnnW, const float* __restrict__ cnnb,
        const float* __restrict__ W1, unsigned short* __restrict__ h1b) {
    __shared__ float s_fcW[32 * 32];
    __shared__ float s_cnnW[128 * 32];
    __shared__ float s_W1[64 * 32];
    __shared__ float s_fcb[32], s_cnnb[32];
    __shared__ float s_x[4][32];
    __shared__ float s_cnn[4][128];
    __shared__ float s_h0[4][64];

    const int tid = threadIdx.x;
    for (int i = tid; i < 32 * 32; i += 256) s_fcW[i] = fcW[i];
    for (int i = tid; i < 128 * 32; i += 256) s_cnnW[i] = cnnW[i];
    for (int i = tid; i < 64 * 32; i += 256) s_W1[i] = W1[i];
    if (tid < 32) { s_fcb[tid] = fcb[tid]; s_cnnb[tid] = cnnb[tid]; }
    __syncthreads();

    const int local = tid >> 6;
    const int lane = tid & 63;

    for (int tile = blockIdx.x; tile < N_NODES / 4; tile += gridDim.x) {
        const int node = tile * 4 + local;
        if (lane < 32) s_x[local][lane] = x[node * 32 + lane];
        s_cnn[local][lane] = cnn[node * 128 + lane];
        s_cnn[local][lane + 64] = cnn[node * 128 + lane + 64];
        __syncthreads();

        float h0v;
        if (lane < 32) {
            float acc = s_fcb[lane];
            #pragma unroll
            for (int f = 0; f < 32; ++f) acc = fmaf(s_x[local][f], s_fcW[f * 32 + lane], acc);
            h0v = fmaxf(acc, 0.0f);
        } else {
            const int k = lane - 32;
            float acc = s_cnnb[k];
            #pragma unroll 8
            for (int f = 0; f < 128; ++f) acc = fmaf(s_cnn[local][f], s_cnnW[f * 32 + k], acc);
            h0v = fmaxf(acc, 0.0f);
        }
        s_h0[local][lane] = h0v;
        __syncthreads();

        if (lane < 32) {
            float acc = 0.0f;
            #pragma unroll
            for (int k = 0; k < 64; ++k) acc = fmaf(s_h0[local][k], s_W1[k * 32 + lane], acc);
            h1b[node * 32 + lane] = f2bf(acc);
        }
    }
}

// ---------- conv1: gather(bf16) + ReLU + GEMM2 -> h2(bf16); 1 node/wave ----------
__global__ __launch_bounds__(256) void conv1_fused(
        const unsigned short* __restrict__ h1b, const int* __restrict__ row,
        const int* __restrict__ ss, const float* __restrict__ dinv,
        const float* __restrict__ b1, const float* __restrict__ W2,
        unsigned short* __restrict__ h2b) {
    __shared__ float sW2[32 * 20];
    __shared__ float sb1[32];
    __shared__ float sa[4][33];
    const int tid = threadIdx.x;
    for (int i = tid; i < 32 * 20; i += 256) sW2[i] = W2[i];
    if (tid < 32) sb1[tid] = b1[tid];
    __syncthreads();   // stage-before-use barrier (R3 lesson)

    const int wid = tid >> 6;
    const int lane = tid & 63;
    const int col = lane & 31;
    const int half = lane >> 5;
    const int node = blockIdx.x * 4 + wid;   // grid 25000 exact

    const float di = dinv[node];
    float acc = (half == 0) ? bf2f(h1b[node * 32 + col]) * di * di + sb1[col] : 0.0f;
    const int end = row[node + 1];
    int i = row[node] + half;
    // 4-deep unroll per half: 8 gathers in flight per wave
    for (; i + 6 < end; i += 8) {
        const int s0 = ss[i], s1 = ss[i + 2], s2 = ss[i + 4], s3 = ss[i + 6];
        const float w0 = dinv[s0] * di, w1 = dinv[s1] * di;
        const float w2 = dinv[s2] * di, w3 = dinv[s3] * di;
        const float v0 = bf2f(h1b[s0 * 32 + col]), v1 = bf2f(h1b[s1 * 32 + col]);
        const float v2 = bf2f(h1b[s2 * 32 + col]), v3 = bf2f(h1b[s3 * 32 + col]);
        acc = fmaf(v0, w0, acc);
        acc = fmaf(v1, w1, acc);
        acc = fmaf(v2, w2, acc);
        acc = fmaf(v3, w3, acc);
    }
    for (; i < end; i += 2) {
        const int s = ss[i];
        acc = fmaf(bf2f(h1b[s * 32 + col]), dinv[s] * di, acc);
    }
    acc += __shfl_xor(acc, 32);
    if (half == 0) sa[wid][col] = fmaxf(acc, 0.0f);
    __syncthreads();

    if (lane < 20) {
        float o = 0.0f;
        #pragma unroll
        for (int k = 0; k < 32; ++k) o = fmaf(sa[wid][k], sW2[k * 20 + lane], o);
        h2b[node * 20 + lane] = f2bf(o);
    }
}

// ---------- conv2: gather(bf16) -> out(f32) ----------
__global__ __launch_bounds__(256) void conv2_gather(
        const unsigned short* __restrict__ h2b, const int* __restrict__ row,
        const int* __restrict__ ss, const float* __restrict__ dinv,
        const float* __restrict__ b2, float* __restrict__ out) {
    __shared__ float sb2[20];
    const int tid = threadIdx.x;
    if (tid < 20) sb2[tid] = b2[tid];
    __syncthreads();

    const int wid = tid >> 6, lane = tid & 63;
    const int col = lane & 31, half = lane >> 5;
    const int node = blockIdx.x * 4 + wid;
    const bool act = (col < 20);

    const float di = dinv[node];
    float acc = 0.0f;
    if (half == 0 && act) acc = bf2f(h2b[node * 20 + col]) * di * di + sb2[col];
    const int end = row[node + 1];
    int i = row[node] + half;
    for (; i + 6 < end; i += 8) {
        const int s0 = ss[i], s1 = ss[i + 2], s2 = ss[i + 4], s3 = ss[i + 6];
        if (act) {
            const float w0 = dinv[s0] * di, w1 = dinv[s1] * di;
            const float w2 = dinv[s2] * di, w3 = dinv[s3] * di;
            const float v0 = bf2f(h2b[s0 * 20 + col]), v1 = bf2f(h2b[s1 * 20 + col]);
            const float v2 = bf2f(h2b[s2 * 20 + col]), v3 = bf2f(h2b[s3 * 20 + col]);
            acc = fmaf(v0, w0, acc);
            acc = fmaf(v1, w1, acc);
            acc = fmaf(v2, w2, acc);
            acc = fmaf(v3, w3, acc);
        }
    }
    for (; i < end; i += 2) {
        const int s = ss[i];
        if (act) acc = fmaf(bf2f(h2b[s * 20 + col]), dinv[s] * di, acc);
    }
    acc += __shfl_xor(acc, 32);
    if (half == 0 && act) out[node * 20 + col] = acc;
}

extern "C" void kernel_launch(void* const* d_in, const int* in_sizes, int n_in,
                              void* d_out, int out_size, void* d_ws, size_t ws_size,
                              hipStream_t stream) {
    const float* x    = (const float*)d_in[0];
    const float* cnn  = (const float*)d_in[1];
    const int*   ei   = (const int*)d_in[2];
    const float* fcW  = (const float*)d_in[3];
    const float* fcb  = (const float*)d_in[4];
    const float* cnnW = (const float*)d_in[5];
    const float* cnnb = (const float*)d_in[6];
    const float* W1   = (const float*)d_in[7];
    const float* b1   = (const float*)d_in[8];
    const float* W2   = (const float*)d_in[9];
    const float* b2   = (const float*)d_in[10];

    const int* srcp = ei;
    const int* dstp = ei + N_EDGES;

    // workspace layout (4-byte units), total ~37 MB
    float* ws      = (float*)d_ws;
    int*   deg     = (int*)ws;                  // [100352]
    float* dinv    = ws + 100352;               // [100352]
    int*   row     = (int*)(ws + 200704);       // [100608] (N+1 used)
    int*   bsum    = (int*)(ws + 301312);       // [512]
    int*   bktcnt  = (int*)(ws + 301824);       // [512]
    int*   bktbase = (int*)(ws + 302336);       // [512] (NBKT+1 used)
    int*   bktcur  = (int*)(ws + 302848);       // [512]
    int*   pairs   = (int*)(ws + 303360);       // [N_EDGES] packed (src<<8|dl)
    int*   sorted  = (int*)(ws + 303360 + N_EDGES);            // [N_EDGES]
    unsigned short* h1b = (unsigned short*)(ws + 303360 + 2 * N_EDGES);  // [N*32] bf16
    unsigned short* h2b = h1b + N_NODES * 32;                  // [N*20] bf16
    float* out     = (float*)d_out;

    // --- bucketed CSR build ---
    hipMemsetAsync(bktcnt, 0, 512 * sizeof(int), stream);
    bucket_hist<<<NBLK_E, 256, 0, stream>>>(dstp, bktcnt);
    bucket_scan<<<1, 512, 0, stream>>>(bktcnt, bktbase, bktcur);
    bucket_scatter<<<NBLK_E, 256, 0, stream>>>(srcp, dstp, bktcur, pairs);
    bucket_deg<<<NBKT, 256, 0, stream>>>(pairs, bktbase, deg, dinv);
    scan1<<<SCAN_NB, 256, 0, stream>>>(deg, row, bsum);
    scan2<<<1, 512, 0, stream>>>(bsum);
    scan3<<<SCAN_NB, 256, 0, stream>>>(row, bsum);
    csr_fill<<<NBKT, 256, 0, stream>>>(pairs, bktbase, row, sorted);

    // --- encoder + first linear (persistent) ---
    encoder_gemm1<<<1280, 256, 0, stream>>>(x, cnn, fcW, fcb, cnnW, cnnb, W1, h1b);

    // --- conv1 gather + relu + gemm2 ---
    conv1_fused<<<N_NODES / 4, 256, 0, stream>>>(h1b, row, sorted, dinv, b1, W2, h2b);

    // --- conv2 gather -> out ---
    conv2_gather<<<N_NODES / 4, 256, 0, stream>>>(h2b, row, sorted, dinv, b2, out);
}

// Round 10
// 438.607 us; speedup vs baseline: 2.5581x; 1.2260x over previous
//
#include <hip/hip_runtime.h>

#define N_NODES 100000
#define N_EDGES 3200000
#define NBKT 391     // ceil(100000/256): buckets of 256 dst nodes
#define EPB 4096     // edges per block in bucket passes
#define NBLK_E 782   // ceil(N_EDGES/EPB)
#define SCAN_NB 391  // ceil(100000/256) node-scan blocks
#define NT 25000     // encoder node tiles (4 nodes each)

// bf16 helpers (round-to-nearest-even pack, cheap unpack)
__device__ __forceinline__ unsigned short f2bf(float f) {
    unsigned int u = __float_as_uint(f);
    u += 0x7fff + ((u >> 16) & 1);
    return (unsigned short)(u >> 16);
}
__device__ __forceinline__ float bf2f(unsigned short h) {
    return __uint_as_float(((unsigned int)h) << 16);
}

// ---------- pass A: per-bucket edge counts (LDS-aggregated) ----------
__global__ __launch_bounds__(256) void bucket_hist(const int* __restrict__ dst,
                                                   int* __restrict__ bktcnt) {
    __shared__ int h[NBKT];
    for (int i = threadIdx.x; i < NBKT; i += 256) h[i] = 0;
    __syncthreads();
    const int base = blockIdx.x * EPB;
    #pragma unroll
    for (int k = 0; k < 16; ++k) {
        const int e = base + k * 256 + threadIdx.x;
        if (e < N_EDGES) atomicAdd(&h[dst[e] >> 8], 1);
    }
    __syncthreads();
    for (int i = threadIdx.x; i < NBKT; i += 256)
        if (h[i]) atomicAdd(&bktcnt[i], h[i]);
}

// ---------- scan of bucket counts -> bases + cursors (1 block) ----------
__global__ void bucket_scan(const int* __restrict__ bktcnt, int* __restrict__ bktbase,
                            int* __restrict__ bktcur) {
    __shared__ int s[512];
    const int t = threadIdx.x;
    const int v = (t < NBKT) ? bktcnt[t] : 0;
    s[t] = v;
    __syncthreads();
    #pragma unroll
    for (int off = 1; off < 512; off <<= 1) {
        const int u = (t >= off) ? s[t - off] : 0;
        __syncthreads();
        s[t] += u;
        __syncthreads();
    }
    if (t <= NBKT) {
        const int b = s[t] - v;
        bktbase[t] = b;
        if (t < NBKT) bktcur[t] = b;
    }
}

// ---------- pass B: chunked scatter of packed (src<<8 | dstlocal) ----------
__global__ __launch_bounds__(256) void bucket_scatter(const int* __restrict__ src,
                                                      const int* __restrict__ dst,
                                                      int* __restrict__ bktcur,
                                                      int* __restrict__ pairs) {
    __shared__ int h[NBKT], gb[NBKT], lc[NBKT];
    for (int i = threadIdx.x; i < NBKT; i += 256) h[i] = 0;
    __syncthreads();
    const int base = blockIdx.x * EPB;
    int v[16], bk[16];
    #pragma unroll
    for (int k = 0; k < 16; ++k) {
        const int e = base + k * 256 + threadIdx.x;
        if (e < N_EDGES) {
            const int d = dst[e];
            bk[k] = d >> 8;
            v[k] = (src[e] << 8) | (d & 255);
            atomicAdd(&h[bk[k]], 1);
        } else {
            bk[k] = -1;
        }
    }
    __syncthreads();
    for (int i = threadIdx.x; i < NBKT; i += 256) {
        gb[i] = h[i] ? atomicAdd(&bktcur[i], h[i]) : 0;
        lc[i] = 0;
    }
    __syncthreads();
    #pragma unroll
    for (int k = 0; k < 16; ++k) {
        if (bk[k] >= 0) {
            const int pos = gb[bk[k]] + atomicAdd(&lc[bk[k]], 1);
            pairs[pos] = v[k];
        }
    }
}

// ---------- pass C1: per-bucket dst degrees via LDS hist; also emits dinv ----------
__global__ __launch_bounds__(256) void bucket_deg(const int* __restrict__ pairs,
                                                  const int* __restrict__ bktbase,
                                                  int* __restrict__ deg,
                                                  float* __restrict__ dinv) {
    __shared__ int h[256];
    h[threadIdx.x] = 0;
    __syncthreads();
    const int b = blockIdx.x;
    const int s0 = bktbase[b], s1 = bktbase[b + 1];
    for (int i = s0 + threadIdx.x; i < s1; i += 256) atomicAdd(&h[pairs[i] & 255], 1);
    __syncthreads();
    const int node = (b << 8) + threadIdx.x;
    if (node < N_NODES) {
        const int c = h[threadIdx.x];
        deg[node] = c;
        dinv[node] = rsqrtf((float)c + 1.0f);
    }
}

// ---------- 3-kernel exclusive scan of deg -> row ----------
__global__ void scan1(const int* __restrict__ cnt, int* __restrict__ row,
                      int* __restrict__ bsum) {
    __shared__ int s[256];
    const int i = blockIdx.x * 256 + threadIdx.x;
    const int v = (i < N_NODES) ? cnt[i] : 0;
    s[threadIdx.x] = v;
    __syncthreads();
    #pragma unroll
    for (int off = 1; off < 256; off <<= 1) {
        const int t = (threadIdx.x >= off) ? s[threadIdx.x - off] : 0;
        __syncthreads();
        s[threadIdx.x] += t;
        __syncthreads();
    }
    if (i < N_NODES) row[i] = s[threadIdx.x] - v;
    if (threadIdx.x == 255) bsum[blockIdx.x] = s[255];
}

__global__ void scan2(int* __restrict__ bsum) {
    __shared__ int s[512];
    const int v = (threadIdx.x < SCAN_NB) ? bsum[threadIdx.x] : 0;
    s[threadIdx.x] = v;
    __syncthreads();
    #pragma unroll
    for (int off = 1; off < 512; off <<= 1) {
        const int t = (threadIdx.x >= off) ? s[threadIdx.x - off] : 0;
        __syncthreads();
        s[threadIdx.x] += t;
        __syncthreads();
    }
    if (threadIdx.x < SCAN_NB) bsum[threadIdx.x] = s[threadIdx.x] - v;
}

__global__ void scan3(int* __restrict__ row, const int* __restrict__ bsum) {
    const int i = blockIdx.x * 256 + threadIdx.x;
    if (i < N_NODES) row[i] += bsum[blockIdx.x];
    if (blockIdx.x == 0 && threadIdx.x == 0) row[N_NODES] = N_EDGES;  // sentinel
}

// ---------- pass C2: per-bucket CSR fill ----------
__global__ __launch_bounds__(256) void csr_fill(const int* __restrict__ pairs,
                                                const int* __restrict__ bktbase,
                                                const int* __restrict__ row,
                                                int* __restrict__ sorted_src) {
    __shared__ int lc[256];
    lc[threadIdx.x] = 0;
    __syncthreads();
    const int b = blockIdx.x;
    const int s0 = bktbase[b], s1 = bktbase[b + 1];
    const int nbase = b << 8;
    for (int i = s0 + threadIdx.x; i < s1; i += 256) {
        const int p = pairs[i];
        const int dl = p & 255;
        const int pos = row[nbase + dl] + atomicAdd(&lc[dl], 1);
        sorted_src[pos] = p >> 8;
    }
}

// ---------- encoder + GEMM1, v2: reg-weights, balanced split, barrier-free loop ----------
// 256 thr = 4 waves; 1 node/wave/iter. Lane l: output o=l&31, half h=l>>5.
// Per-lane weight slices live in VGPRs (statically indexed, fully unrolled).
// LDS input slots are wave-private -> NO in-loop __syncthreads (DS is in-order
// per wave). Next node's x/cnn prefetched into regs under current compute.
__global__ __launch_bounds__(256) void encoder_gemm1(
        const float* __restrict__ x, const float* __restrict__ cnn,
        const float* __restrict__ fcW, const float* __restrict__ fcb,
        const float* __restrict__ cnnW, const float* __restrict__ cnnb,
        const float* __restrict__ W1, unsigned short* __restrict__ h1b) {
    __shared__ float s_fcW[32 * 32];
    __shared__ float s_cnnW[128 * 32];
    __shared__ float s_W1[64 * 32];
    __shared__ float s_fcb[32], s_cnnb[32];
    __shared__ float s_in[4][160];   // [wave][0:32)=x row, [32:160)=cnn row
    __shared__ float s_h0[4][64];

    const int tid = threadIdx.x;
    for (int i = tid; i < 32 * 32; i += 256) s_fcW[i] = fcW[i];
    for (int i = tid; i < 128 * 32; i += 256) s_cnnW[i] = cnnW[i];
    for (int i = tid; i < 64 * 32; i += 256) s_W1[i] = W1[i];
    if (tid < 32) { s_fcb[tid] = fcb[tid]; s_cnnb[tid] = cnnb[tid]; }
    __syncthreads();   // one-time: staging -> all-wave reads below

    const int wid = tid >> 6, lane = tid & 63;
    const int o = lane & 31, h = lane >> 5;

    // per-lane weight slices -> registers (static indices only)
    float wfc[16], wcn[64], w1r[32];
    #pragma unroll
    for (int j = 0; j < 16; ++j) wfc[j] = s_fcW[(16 * h + j) * 32 + o];
    #pragma unroll
    for (int j = 0; j < 64; ++j) wcn[j] = s_cnnW[(64 * h + j) * 32 + o];
    #pragma unroll
    for (int j = 0; j < 32; ++j) w1r[j] = s_W1[(32 * h + j) * 32 + o];
    const float bfc = s_fcb[o], bcn = s_cnnb[o];

    float* sin_ = s_in[wid];
    float* sh0 = s_h0[wid];

    // prologue: load first tile's inputs into regs
    int tile = blockIdx.x;
    int node = tile * 4 + wid;
    float xv = (lane < 32) ? x[node * 32 + lane] : 0.0f;
    float c0 = cnn[node * 128 + lane];
    float c1 = cnn[node * 128 + 64 + lane];

    for (; tile < NT; tile += gridDim.x) {
        node = tile * 4 + wid;
        // 1. spill current node's inputs to my wave slot (cross-lane access)
        if (lane < 32) sin_[lane] = xv;
        sin_[32 + lane] = c0;
        sin_[96 + lane] = c1;
        // 2. prefetch next tile's inputs (latency hidden under compute)
        const int ntile = tile + gridDim.x;
        const int nnode = (ntile < NT) ? ntile * 4 + wid : node;
        xv = (lane < 32) ? x[nnode * 32 + lane] : 0.0f;
        c0 = cnn[nnode * 128 + lane];
        c1 = cnn[nnode * 128 + 64 + lane];
        // 3. h0 partials: fc (16 MACs) + cnn (64 MACs), balanced across lanes
        float afc = 0.0f, acn = 0.0f;
        #pragma unroll
        for (int j = 0; j < 16; j += 4) {
            const float4 iv = *reinterpret_cast<const float4*>(&sin_[16 * h + j]);
            afc = fmaf(iv.x, wfc[j], afc);
            afc = fmaf(iv.y, wfc[j + 1], afc);
            afc = fmaf(iv.z, wfc[j + 2], afc);
            afc = fmaf(iv.w, wfc[j + 3], afc);
        }
        #pragma unroll
        for (int j = 0; j < 64; j += 4) {
            const float4 iv = *reinterpret_cast<const float4*>(&sin_[32 + 64 * h + j]);
            acn = fmaf(iv.x, wcn[j], acn);
            acn = fmaf(iv.y, wcn[j + 1], acn);
            acn = fmaf(iv.z, wcn[j + 2], acn);
            acn = fmaf(iv.w, wcn[j + 3], acn);
        }
        afc += __shfl_xor(afc, 32);
        acn += __shfl_xor(acn, 32);
        // lane l holds h0[l]: l<32 -> fc branch, l>=32 -> cnn branch
        const float h0v = (lane < 32) ? fmaxf(afc + bfc, 0.0f)
                                      : fmaxf(acn + bcn, 0.0f);
        sh0[lane] = h0v;
        // 4. h1 = h0 @ W1 (32 MACs/lane + combine)
        float a1 = 0.0f;
        #pragma unroll
        for (int j = 0; j < 32; j += 4) {
            const float4 iv = *reinterpret_cast<const float4*>(&sh0[32 * h + j]);
            a1 = fmaf(iv.x, w1r[j], a1);
            a1 = fmaf(iv.y, w1r[j + 1], a1);
            a1 = fmaf(iv.z, w1r[j + 2], a1);
            a1 = fmaf(iv.w, w1r[j + 3], a1);
        }
        a1 += __shfl_xor(a1, 32);
        if (lane < 32) h1b[node * 32 + o] = f2bf(a1);
    }
}

// ---------- conv1: gather(bf16) + ReLU + GEMM2 -> h2(bf16); 1 node/wave ----------
__global__ __launch_bounds__(256) void conv1_fused(
        const unsigned short* __restrict__ h1b, const int* __restrict__ row,
        const int* __restrict__ ss, const float* __restrict__ dinv,
        const float* __restrict__ b1, const float* __restrict__ W2,
        unsigned short* __restrict__ h2b) {
    __shared__ float sW2[32 * 20];
    __shared__ float sb1[32];
    __shared__ float sa[4][33];
    const int tid = threadIdx.x;
    for (int i = tid; i < 32 * 20; i += 256) sW2[i] = W2[i];
    if (tid < 32) sb1[tid] = b1[tid];
    __syncthreads();   // stage-before-use barrier (R3 lesson)

    const int wid = tid >> 6;
    const int lane = tid & 63;
    const int col = lane & 31;
    const int half = lane >> 5;
    const int node = blockIdx.x * 4 + wid;   // grid 25000 exact

    const float di = dinv[node];
    float acc = (half == 0) ? bf2f(h1b[node * 32 + col]) * di * di + sb1[col] : 0.0f;
    const int end = row[node + 1];
    int i = row[node] + half;
    // 4-deep unroll per half: 8 gathers in flight per wave
    for (; i + 6 < end; i += 8) {
        const int s0 = ss[i], s1 = ss[i + 2], s2 = ss[i + 4], s3 = ss[i + 6];
        const float w0 = dinv[s0] * di, w1 = dinv[s1] * di;
        const float w2 = dinv[s2] * di, w3 = dinv[s3] * di;
        const float v0 = bf2f(h1b[s0 * 32 + col]), v1 = bf2f(h1b[s1 * 32 + col]);
        const float v2 = bf2f(h1b[s2 * 32 + col]), v3 = bf2f(h1b[s3 * 32 + col]);
        acc = fmaf(v0, w0, acc);
        acc = fmaf(v1, w1, acc);
        acc = fmaf(v2, w2, acc);
        acc = fmaf(v3, w3, acc);
    }
    for (; i < end; i += 2) {
        const int s = ss[i];
        acc = fmaf(bf2f(h1b[s * 32 + col]), dinv[s] * di, acc);
    }
    acc += __shfl_xor(acc, 32);
    if (half == 0) sa[wid][col] = fmaxf(acc, 0.0f);
    __syncthreads();

    if (lane < 20) {
        float o = 0.0f;
        #pragma unroll
        for (int k = 0; k < 32; ++k) o = fmaf(sa[wid][k], sW2[k * 20 + lane], o);
        h2b[node * 20 + lane] = f2bf(o);
    }
}

// ---------- conv2: gather(bf16) -> out(f32) ----------
__global__ __launch_bounds__(256) void conv2_gather(
        const unsigned short* __restrict__ h2b, const int* __restrict__ row,
        const int* __restrict__ ss, const float* __restrict__ dinv,
        const float* __restrict__ b2, float* __restrict__ out) {
    __shared__ float sb2[20];
    const int tid = threadIdx.x;
    if (tid < 20) sb2[tid] = b2[tid];
    __syncthreads();

    const int wid = tid >> 6, lane = tid & 63;
    const int col = lane & 31, half = lane >> 5;
    const int node = blockIdx.x * 4 + wid;
    const bool act = (col < 20);

    const float di = dinv[node];
    float acc = 0.0f;
    if (half == 0 && act) acc = bf2f(h2b[node * 20 + col]) * di * di + sb2[col];
    const int end = row[node + 1];
    int i = row[node] + half;
    for (; i + 6 < end; i += 8) {
        const int s0 = ss[i], s1 = ss[i + 2], s2 = ss[i + 4], s3 = ss[i + 6];
        if (act) {
            const float w0 = dinv[s0] * di, w1 = dinv[s1] * di;
            const float w2 = dinv[s2] * di, w3 = dinv[s3] * di;
            const float v0 = bf2f(h2b[s0 * 20 + col]), v1 = bf2f(h2b[s1 * 20 + col]);
            const float v2 = bf2f(h2b[s2 * 20 + col]), v3 = bf2f(h2b[s3 * 20 + col]);
            acc = fmaf(v0, w0, acc);
            acc = fmaf(v1, w1, acc);
            acc = fmaf(v2, w2, acc);
            acc = fmaf(v3, w3, acc);
        }
    }
    for (; i < end; i += 2) {
        const int s = ss[i];
        if (act) acc = fmaf(bf2f(h2b[s * 20 + col]), dinv[s] * di, acc);
    }
    acc += __shfl_xor(acc, 32);
    if (half == 0 && act) out[node * 20 + col] = acc;
}

extern "C" void kernel_launch(void* const* d_in, const int* in_sizes, int n_in,
                              void* d_out, int out_size, void* d_ws, size_t ws_size,
                              hipStream_t stream) {
    const float* x    = (const float*)d_in[0];
    const float* cnn  = (const float*)d_in[1];
    const int*   ei   = (const int*)d_in[2];
    const float* fcW  = (const float*)d_in[3];
    const float* fcb  = (const float*)d_in[4];
    const float* cnnW = (const float*)d_in[5];
    const float* cnnb = (const float*)d_in[6];
    const float* W1   = (const float*)d_in[7];
    const float* b1   = (const float*)d_in[8];
    const float* W2   = (const float*)d_in[9];
    const float* b2   = (const float*)d_in[10];

    const int* srcp = ei;
    const int* dstp = ei + N_EDGES;

    // workspace layout (4-byte units), total ~37 MB
    float* ws      = (float*)d_ws;
    int*   deg     = (int*)ws;                  // [100352]
    float* dinv    = ws + 100352;               // [100352]
    int*   row     = (int*)(ws + 200704);       // [100608] (N+1 used)
    int*   bsum    = (int*)(ws + 301312);       // [512]
    int*   bktcnt  = (int*)(ws + 301824);       // [512]
    int*   bktbase = (int*)(ws + 302336);       // [512] (NBKT+1 used)
    int*   bktcur  = (int*)(ws + 302848);       // [512]
    int*   pairs   = (int*)(ws + 303360);       // [N_EDGES] packed (src<<8|dl)
    int*   sorted  = (int*)(ws + 303360 + N_EDGES);            // [N_EDGES]
    unsigned short* h1b = (unsigned short*)(ws + 303360 + 2 * N_EDGES);  // [N*32] bf16
    unsigned short* h2b = h1b + N_NODES * 32;                  // [N*20] bf16
    float* out     = (float*)d_out;

    // --- bucketed CSR build ---
    hipMemsetAsync(bktcnt, 0, 512 * sizeof(int), stream);
    bucket_hist<<<NBLK_E, 256, 0, stream>>>(dstp, bktcnt);
    bucket_scan<<<1, 512, 0, stream>>>(bktcnt, bktbase, bktcur);
    bucket_scatter<<<NBLK_E, 256, 0, stream>>>(srcp, dstp, bktcur, pairs);
    bucket_deg<<<NBKT, 256, 0, stream>>>(pairs, bktbase, deg, dinv);
    scan1<<<SCAN_NB, 256, 0, stream>>>(deg, row, bsum);
    scan2<<<1, 512, 0, stream>>>(bsum);
    scan3<<<SCAN_NB, 256, 0, stream>>>(row, bsum);
    csr_fill<<<NBKT, 256, 0, stream>>>(pairs, bktbase, row, sorted);

    // --- encoder + first linear (persistent, barrier-free loop) ---
    encoder_gemm1<<<1280, 256, 0, stream>>>(x, cnn, fcW, fcb, cnnW, cnnb, W1, h1b);

    // --- conv1 gather + relu + gemm2 ---
    conv1_fused<<<N_NODES / 4, 256, 0, stream>>>(h1b, row, sorted, dinv, b1, W2, h2b);

    // --- conv2 gather -> out ---
    conv2_gather<<<N_NODES / 4, 256, 0, stream>>>(h2b, row, sorted, dinv, b2, out);
}

// Round 12
// 406.208 us; speedup vs baseline: 2.7621x; 1.0798x over previous
//
#include <hip/hip_runtime.h>

#define N_NODES 100000
#define N_EDGES 3200000
#define NBKT 391     // ceil(100000/256): buckets of 256 dst nodes
#define EPB 8192     // edges per block in bucket passes
#define NBLK_E 391   // ceil(N_EDGES/EPB)
#define NT 25000     // encoder node tiles (4 nodes each)

// bf16 helpers (round-to-nearest-even pack, cheap unpack)
__device__ __forceinline__ unsigned short f2bf(float f) {
    unsigned int u = __float_as_uint(f);
    u += 0x7fff + ((u >> 16) & 1);
    return (unsigned short)(u >> 16);
}
__device__ __forceinline__ float bf2f(unsigned short h) {
    return __uint_as_float(((unsigned int)h) << 16);
}

// ---------- pass A: per-bucket edge counts (LDS-aggregated) ----------
__global__ __launch_bounds__(256) void bucket_hist(const int* __restrict__ dst,
                                                   int* __restrict__ bktcnt) {
    __shared__ int h[NBKT];
    for (int i = threadIdx.x; i < NBKT; i += 256) h[i] = 0;
    __syncthreads();
    const int base = blockIdx.x * EPB;
    #pragma unroll
    for (int k = 0; k < 32; ++k) {
        const int e = base + k * 256 + threadIdx.x;
        if (e < N_EDGES) atomicAdd(&h[dst[e] >> 8], 1);
    }
    __syncthreads();
    for (int i = threadIdx.x; i < NBKT; i += 256)
        if (h[i]) atomicAdd(&bktcnt[i], h[i]);
}

// ---------- scan of bucket counts -> bases + cursors (1 block) ----------
__global__ void bucket_scan(const int* __restrict__ bktcnt, int* __restrict__ bktbase,
                            int* __restrict__ bktcur) {
    __shared__ int s[512];
    const int t = threadIdx.x;
    const int v = (t < NBKT) ? bktcnt[t] : 0;
    s[t] = v;
    __syncthreads();
    #pragma unroll
    for (int off = 1; off < 512; off <<= 1) {
        const int u = (t >= off) ? s[t - off] : 0;
        __syncthreads();
        s[t] += u;
        __syncthreads();
    }
    if (t <= NBKT) {
        const int b = s[t] - v;
        bktbase[t] = b;
        if (t < NBKT) bktcur[t] = b;
    }
}

// ---------- pass B: chunked scatter of packed (src<<8 | dstlocal) ----------
__global__ __launch_bounds__(256) void bucket_scatter(const int* __restrict__ src,
                                                      const int* __restrict__ dst,
                                                      int* __restrict__ bktcur,
                                                      int* __restrict__ pairs) {
    __shared__ int h[NBKT], gb[NBKT], lc[NBKT];
    for (int i = threadIdx.x; i < NBKT; i += 256) h[i] = 0;
    __syncthreads();
    const int base = blockIdx.x * EPB;
    int v[32], bk[32];
    #pragma unroll
    for (int k = 0; k < 32; ++k) {
        const int e = base + k * 256 + threadIdx.x;
        if (e < N_EDGES) {
            const int d = dst[e];
            bk[k] = d >> 8;
            v[k] = (src[e] << 8) | (d & 255);
            atomicAdd(&h[bk[k]], 1);
        } else {
            bk[k] = -1;
        }
    }
    __syncthreads();
    for (int i = threadIdx.x; i < NBKT; i += 256) {
        gb[i] = h[i] ? atomicAdd(&bktcur[i], h[i]) : 0;
        lc[i] = 0;
    }
    __syncthreads();
    #pragma unroll
    for (int k = 0; k < 32; ++k) {
        if (bk[k] >= 0) {
            const int pos = gb[bk[k]] + atomicAdd(&lc[bk[k]], 1);
            pairs[pos] = v[k];
        }
    }
}

// ---------- pass C1: per-bucket degrees -> dinv AND row (in-block scan) ----------
// row[node] = bktbase[b] + exclusive-scan of local degrees: replaces the old
// global 3-kernel scan (bucket layout makes it block-local).
__global__ __launch_bounds__(256) void bucket_deg(const int* __restrict__ pairs,
                                                  const int* __restrict__ bktbase,
                                                  float* __restrict__ dinv,
                                                  int* __restrict__ row) {
    __shared__ int h[256];
    __shared__ int sc[256];
    h[threadIdx.x] = 0;
    __syncthreads();
    const int b = blockIdx.x;
    const int s0 = bktbase[b], s1 = bktbase[b + 1];
    for (int i = s0 + threadIdx.x; i < s1; i += 256) atomicAdd(&h[pairs[i] & 255], 1);
    __syncthreads();
    const int c = h[threadIdx.x];
    sc[threadIdx.x] = c;
    __syncthreads();
    #pragma unroll
    for (int off = 1; off < 256; off <<= 1) {
        const int t = (threadIdx.x >= off) ? sc[threadIdx.x - off] : 0;
        __syncthreads();
        sc[threadIdx.x] += t;
        __syncthreads();
    }
    const int node = (b << 8) + threadIdx.x;
    if (node < N_NODES) {
        dinv[node] = rsqrtf((float)c + 1.0f);
        row[node] = s0 + sc[threadIdx.x] - c;   // exclusive prefix
    }
    if (node == N_NODES) row[N_NODES] = N_EDGES;  // sentinel (b=390, tid=160)
}

// ---------- pass C2: per-bucket CSR fill ----------
__global__ __launch_bounds__(256) void csr_fill(const int* __restrict__ pairs,
                                                const int* __restrict__ bktbase,
                                                const int* __restrict__ row,
                                                int* __restrict__ sorted_src) {
    __shared__ int lc[256];
    lc[threadIdx.x] = 0;
    __syncthreads();
    const int b = blockIdx.x;
    const int s0 = bktbase[b], s1 = bktbase[b + 1];
    const int nbase = b << 8;
    for (int i = s0 + threadIdx.x; i < s1; i += 256) {
        const int p = pairs[i];
        const int dl = p & 255;
        const int pos = row[nbase + dl] + atomicAdd(&lc[dl], 1);
        sorted_src[pos] = p >> 8;
    }
}

// ---------- encoder + GEMM1 (reg-weights, barrier-free loop; unchanged R8) ----------
__global__ __launch_bounds__(256) void encoder_gemm1(
        const float* __restrict__ x, const float* __restrict__ cnn,
        const float* __restrict__ fcW, const float* __restrict__ fcb,
        const float* __restrict__ cnnW, const float* __restrict__ cnnb,
        const float* __restrict__ W1, unsigned short* __restrict__ h1b) {
    __shared__ float s_fcW[32 * 32];
    __shared__ float s_cnnW[128 * 32];
    __shared__ float s_W1[64 * 32];
    __shared__ float s_fcb[32], s_cnnb[32];
    __shared__ float s_in[4][160];   // [wave][0:32)=x row, [32:160)=cnn row
    __shared__ float s_h0[4][64];

    const int tid = threadIdx.x;
    for (int i = tid; i < 32 * 32; i += 256) s_fcW[i] = fcW[i];
    for (int i = tid; i < 128 * 32; i += 256) s_cnnW[i] = cnnW[i];
    for (int i = tid; i < 64 * 32; i += 256) s_W1[i] = W1[i];
    if (tid < 32) { s_fcb[tid] = fcb[tid]; s_cnnb[tid] = cnnb[tid]; }
    __syncthreads();   // one-time: staging -> all-wave reads below

    const int wid = tid >> 6, lane = tid & 63;
    const int o = lane & 31, h = lane >> 5;

    float wfc[16], wcn[64], w1r[32];
    #pragma unroll
    for (int j = 0; j < 16; ++j) wfc[j] = s_fcW[(16 * h + j) * 32 + o];
    #pragma unroll
    for (int j = 0; j < 64; ++j) wcn[j] = s_cnnW[(64 * h + j) * 32 + o];
    #pragma unroll
    for (int j = 0; j < 32; ++j) w1r[j] = s_W1[(32 * h + j) * 32 + o];
    const float bfc = s_fcb[o], bcn = s_cnnb[o];

    float* sin_ = s_in[wid];
    float* sh0 = s_h0[wid];

    int tile = blockIdx.x;
    int node = tile * 4 + wid;
    float xv = (lane < 32) ? x[node * 32 + lane] : 0.0f;
    float c0 = cnn[node * 128 + lane];
    float c1 = cnn[node * 128 + 64 + lane];

    for (; tile < NT; tile += gridDim.x) {
        node = tile * 4 + wid;
        if (lane < 32) sin_[lane] = xv;
        sin_[32 + lane] = c0;
        sin_[96 + lane] = c1;
        const int ntile = tile + gridDim.x;
        const int nnode = (ntile < NT) ? ntile * 4 + wid : node;
        xv = (lane < 32) ? x[nnode * 32 + lane] : 0.0f;
        c0 = cnn[nnode * 128 + lane];
        c1 = cnn[nnode * 128 + 64 + lane];
        float afc = 0.0f, acn = 0.0f;
        #pragma unroll
        for (int j = 0; j < 16; j += 4) {
            const float4 iv = *reinterpret_cast<const float4*>(&sin_[16 * h + j]);
            afc = fmaf(iv.x, wfc[j], afc);
            afc = fmaf(iv.y, wfc[j + 1], afc);
            afc = fmaf(iv.z, wfc[j + 2], afc);
            afc = fmaf(iv.w, wfc[j + 3], afc);
        }
        #pragma unroll
        for (int j = 0; j < 64; j += 4) {
            const float4 iv = *reinterpret_cast<const float4*>(&sin_[32 + 64 * h + j]);
            acn = fmaf(iv.x, wcn[j], acn);
            acn = fmaf(iv.y, wcn[j + 1], acn);
            acn = fmaf(iv.z, wcn[j + 2], acn);
            acn = fmaf(iv.w, wcn[j + 3], acn);
        }
        afc += __shfl_xor(afc, 32);
        acn += __shfl_xor(acn, 32);
        const float h0v = (lane < 32) ? fmaxf(afc + bfc, 0.0f)
                                      : fmaxf(acn + bcn, 0.0f);
        sh0[lane] = h0v;
        float a1 = 0.0f;
        #pragma unroll
        for (int j = 0; j < 32; j += 4) {
            const float4 iv = *reinterpret_cast<const float4*>(&sh0[32 * h + j]);
            a1 = fmaf(iv.x, w1r[j], a1);
            a1 = fmaf(iv.y, w1r[j + 1], a1);
            a1 = fmaf(iv.z, w1r[j + 2], a1);
            a1 = fmaf(iv.w, w1r[j + 3], a1);
        }
        a1 += __shfl_xor(a1, 32);
        if (lane < 32) h1b[node * 32 + o] = f2bf(a1);
    }
}

// ---------- conv1: gather(bf16) + ReLU + GEMM2 -> h2b (stride 32) ----------
// 1 node/wave; halves split edges; 8-deep unroll = 16 gathers in flight/wave.
__global__ __launch_bounds__(256) void conv1_fused(
        const unsigned short* __restrict__ h1b, const int* __restrict__ row,
        const int* __restrict__ ss, const float* __restrict__ dinv,
        const float* __restrict__ b1, const float* __restrict__ W2,
        unsigned short* __restrict__ h2b) {
    __shared__ float sW2[32 * 20];
    __shared__ float sb1[32];
    __shared__ float sa[4][33];
    const int tid = threadIdx.x;
    for (int i = tid; i < 32 * 20; i += 256) sW2[i] = W2[i];
    if (tid < 32) sb1[tid] = b1[tid];
    __syncthreads();   // stage-before-use barrier (R3 lesson)

    const int wid = tid >> 6;
    const int lane = tid & 63;
    const int col = lane & 31;
    const int half = lane >> 5;
    const int node = blockIdx.x * 4 + wid;   // grid 25000 exact

    const float di = dinv[node];
    float acc = (half == 0) ? bf2f(h1b[node * 32 + col]) * di * di + sb1[col] : 0.0f;
    const int end = row[node + 1];
    int i = row[node] + half;
    for (; i + 14 < end; i += 16) {
        const int s0 = ss[i], s1 = ss[i + 2], s2 = ss[i + 4], s3 = ss[i + 6];
        const int s4 = ss[i + 8], s5 = ss[i + 10], s6 = ss[i + 12], s7 = ss[i + 14];
        const float w0 = dinv[s0] * di, w1 = dinv[s1] * di, w2 = dinv[s2] * di, w3 = dinv[s3] * di;
        const float w4 = dinv[s4] * di, w5 = dinv[s5] * di, w6 = dinv[s6] * di, w7 = dinv[s7] * di;
        const float v0 = bf2f(h1b[s0 * 32 + col]), v1 = bf2f(h1b[s1 * 32 + col]);
        const float v2 = bf2f(h1b[s2 * 32 + col]), v3 = bf2f(h1b[s3 * 32 + col]);
        const float v4 = bf2f(h1b[s4 * 32 + col]), v5 = bf2f(h1b[s5 * 32 + col]);
        const float v6 = bf2f(h1b[s6 * 32 + col]), v7 = bf2f(h1b[s7 * 32 + col]);
        acc = fmaf(v0, w0, acc);
        acc = fmaf(v1, w1, acc);
        acc = fmaf(v2, w2, acc);
        acc = fmaf(v3, w3, acc);
        acc = fmaf(v4, w4, acc);
        acc = fmaf(v5, w5, acc);
        acc = fmaf(v6, w6, acc);
        acc = fmaf(v7, w7, acc);
    }
    for (; i + 6 < end; i += 8) {
        const int s0 = ss[i], s1 = ss[i + 2], s2 = ss[i + 4], s3 = ss[i + 6];
        const float w0 = dinv[s0] * di, w1 = dinv[s1] * di;
        const float w2 = dinv[s2] * di, w3 = dinv[s3] * di;
        const float v0 = bf2f(h1b[s0 * 32 + col]), v1 = bf2f(h1b[s1 * 32 + col]);
        const float v2 = bf2f(h1b[s2 * 32 + col]), v3 = bf2f(h1b[s3 * 32 + col]);
        acc = fmaf(v0, w0, acc);
        acc = fmaf(v1, w1, acc);
        acc = fmaf(v2, w2, acc);
        acc = fmaf(v3, w3, acc);
    }
    for (; i < end; i += 2) {
        const int s = ss[i];
        acc = fmaf(bf2f(h1b[s * 32 + col]), dinv[s] * di, acc);
    }
    acc += __shfl_xor(acc, 32);
    if (half == 0) sa[wid][col] = fmaxf(acc, 0.0f);
    __syncthreads();

    if (lane < 20) {
        float o = 0.0f;
        #pragma unroll
        for (int k = 0; k < 32; ++k) o = fmaf(sa[wid][k], sW2[k * 20 + lane], o);
        h2b[node * 32 + lane] = f2bf(o);   // stride 32: row = one 64B line
    }
}

// ---------- conv2: gather(bf16, stride-32 rows) -> out(f32) ----------
// 3-way lane split: lanes 0-59 = 3 edge-streams x 20 cols (94% util);
// combine via two __shfl. 8-deep unroll = 24 gathers in flight/wave.
__global__ __launch_bounds__(256) void conv2_gather(
        const unsigned short* __restrict__ h2b, const int* __restrict__ row,
        const int* __restrict__ ss, const float* __restrict__ dinv,
        const float* __restrict__ b2, float* __restrict__ out) {
    __shared__ float sb2[20];
    const int tid = threadIdx.x;
    if (tid < 20) sb2[tid] = b2[tid];
    __syncthreads();

    const int wid = tid >> 6, lane = tid & 63;
    const int third = lane / 20;          // 0,1,2 active; 3 = idle (lanes 60-63)
    const int col = lane - third * 20;    // 0..19
    const int node = blockIdx.x * 4 + wid;

    const float di = dinv[node];
    float acc = 0.0f;
    if (third == 0) acc = bf2f(h2b[node * 32 + col]) * di * di + sb2[col];
    const int end = row[node + 1];
    int i = (third < 3) ? row[node] + third : end;
    for (; i + 21 < end; i += 24) {
        const int s0 = ss[i], s1 = ss[i + 3], s2 = ss[i + 6], s3 = ss[i + 9];
        const int s4 = ss[i + 12], s5 = ss[i + 15], s6 = ss[i + 18], s7 = ss[i + 21];
        const float w0 = dinv[s0] * di, w1 = dinv[s1] * di, w2 = dinv[s2] * di, w3 = dinv[s3] * di;
        const float w4 = dinv[s4] * di, w5 = dinv[s5] * di, w6 = dinv[s6] * di, w7 = dinv[s7] * di;
        const float v0 = bf2f(h2b[s0 * 32 + col]), v1 = bf2f(h2b[s1 * 32 + col]);
        const float v2 = bf2f(h2b[s2 * 32 + col]), v3 = bf2f(h2b[s3 * 32 + col]);
        const float v4 = bf2f(h2b[s4 * 32 + col]), v5 = bf2f(h2b[s5 * 32 + col]);
        const float v6 = bf2f(h2b[s6 * 32 + col]), v7 = bf2f(h2b[s7 * 32 + col]);
        acc = fmaf(v0, w0, acc);
        acc = fmaf(v1, w1, acc);
        acc = fmaf(v2, w2, acc);
        acc = fmaf(v3, w3, acc);
        acc = fmaf(v4, w4, acc);
        acc = fmaf(v5, w5, acc);
        acc = fmaf(v6, w6, acc);
        acc = fmaf(v7, w7, acc);
    }
    for (; i < end; i += 3) {
        const int s = ss[i];
        acc = fmaf(bf2f(h2b[s * 32 + col]), dinv[s] * di, acc);
    }
    // fold thirds 1,2 into third 0 (read pre-fold acc of lanes col+20, col+40)
    const float a1 = __shfl(acc, col + 20);
    const float a2 = __shfl(acc, col + 40);
    if (third == 0) out[node * 20 + col] = acc + a1 + a2;
}

extern "C" void kernel_launch(void* const* d_in, const int* in_sizes, int n_in,
                              void* d_out, int out_size, void* d_ws, size_t ws_size,
                              hipStream_t stream) {
    const float* x    = (const float*)d_in[0];
    const float* cnn  = (const float*)d_in[1];
    const int*   ei   = (const int*)d_in[2];
    const float* fcW  = (const float*)d_in[3];
    const float* fcb  = (const float*)d_in[4];
    const float* cnnW = (const float*)d_in[5];
    const float* cnnb = (const float*)d_in[6];
    const float* W1   = (const float*)d_in[7];
    const float* b1   = (const float*)d_in[8];
    const float* W2   = (const float*)d_in[9];
    const float* b2   = (const float*)d_in[10];

    const int* srcp = ei;
    const int* dstp = ei + N_EDGES;

    // workspace layout (4-byte units), total ~36 MB
    float* ws      = (float*)d_ws;
    float* dinv    = ws;                        // [100352]
    int*   row     = (int*)(ws + 100352);       // [100608] (N+1 used)
    int*   bktcnt  = (int*)(ws + 200960);       // [512]
    int*   bktbase = (int*)(ws + 201472);       // [512] (NBKT+1 used)
    int*   bktcur  = (int*)(ws + 201984);       // [512]
    int*   pairs   = (int*)(ws + 202496);       // [N_EDGES] packed (src<<8|dl)
    int*   sorted  = (int*)(ws + 202496 + N_EDGES);            // [N_EDGES]
    unsigned short* h1b = (unsigned short*)(ws + 202496 + 2 * N_EDGES);  // [N*32] bf16
    unsigned short* h2b = h1b + N_NODES * 32;                  // [N*32] bf16 (stride 32)
    float* out     = (float*)d_out;

    // --- bucketed CSR build (6 dispatches incl. memset) ---
    hipMemsetAsync(bktcnt, 0, 512 * sizeof(int), stream);
    bucket_hist<<<NBLK_E, 256, 0, stream>>>(dstp, bktcnt);
    bucket_scan<<<1, 512, 0, stream>>>(bktcnt, bktbase, bktcur);
    bucket_scatter<<<NBLK_E, 256, 0, stream>>>(srcp, dstp, bktcur, pairs);
    bucket_deg<<<NBKT, 256, 0, stream>>>(pairs, bktbase, dinv, row);
    csr_fill<<<NBKT, 256, 0, stream>>>(pairs, bktbase, row, sorted);

    // --- encoder + first linear (persistent, barrier-free loop) ---
    encoder_gemm1<<<1280, 256, 0, stream>>>(x, cnn, fcW, fcb, cnnW, cnnb, W1, h1b);

    // --- conv1 gather + relu + gemm2 ---
    conv1_fused<<<N_NODES / 4, 256, 0, stream>>>(h1b, row, sorted, dinv, b1, W2, h2b);

    // --- conv2 gather -> out ---
    conv2_gather<<<N_NODES / 4, 256, 0, stream>>>(h2b, row, sorted, dinv, b2, out);
}